// Round 1
// baseline (79.775 us; speedup 1.0000x reference)
//
#include <hip/hip_runtime.h>
#include <math.h>

// Problem constants (match reference)
#define BB 64
#define HH 224
#define WW 224
#define CC 3

constexpr float FACTOR  = 0.2f;
constexpr float SCALE_K = 1.0f / 255.0f;
constexpr float TWO_PI_F = 6.283185307179586f;   // rounds to float32 like np
constexpr float CX = (WW - 1) * 0.5f;            // 111.5
constexpr float CY = (HH - 1) * 0.5f;            // 111.5
constexpr int PIX = HH * WW;                     // 50176
constexpr int IMG_ELEMS = PIX * CC;              // 150528

struct BatchParams { float c, s, zh, zw, dx, dy; int flip, pad; };

__global__ void params_kernel(const float* __restrict__ angle_u,
                              const float* __restrict__ zoom_u,
                              const float* __restrict__ shift_u,
                              const float* __restrict__ flip_u,
                              BatchParams* __restrict__ P) {
    int b = threadIdx.x;
    if (b >= BB) return;
    BatchParams p;
    float t = (2.0f * angle_u[b] - 1.0f) * FACTOR;     // mirror ref op order
    float theta = t * TWO_PI_F;
    p.c = cosf(theta);
    p.s = sinf(theta);
    p.zh = 1.0f + (2.0f * zoom_u[2 * b + 0] - 1.0f) * FACTOR;
    p.zw = 1.0f + (2.0f * zoom_u[2 * b + 1] - 1.0f) * FACTOR;
    p.dy = ((2.0f * shift_u[2 * b + 0] - 1.0f) * FACTOR) * (float)HH;
    p.dx = ((2.0f * shift_u[2 * b + 1] - 1.0f) * FACTOR) * (float)WW;
    p.flip = (flip_u[b] > 0.5f) ? 1 : 0;
    p.pad = 0;
    P[b] = p;
}

__device__ __forceinline__ int reflect_idx(int i, int n) {
    int m = i % (2 * n);
    if (m < 0) m += 2 * n;
    return (m >= n) ? (2 * n - 1 - m) : m;
}

// MODE 0: rotate (+rescale), MODE 1: zoom, MODE 2: translate (+flip)
template <int MODE>
__global__ __launch_bounds__(256)
void warp_kernel(const float* __restrict__ src, float* __restrict__ dst,
                 const BatchParams* __restrict__ P) {
    const int b = blockIdx.y;
    const int pix = blockIdx.x * 256 + threadIdx.x;    // gridDim.x*256 == PIX exactly
    const int y = pix / WW;
    const int x = pix - y * WW;

    const BatchParams p = P[b];

    float xs, ys;
    if (MODE == 0) {
        float rx = (float)x - CX;
        float ry = (float)y - CY;
        xs = p.c * rx - p.s * ry + CX;
        ys = p.s * rx + p.c * ry + CY;
    } else if (MODE == 1) {
        xs = p.zw * ((float)x - CX) + CX;
        ys = p.zh * ((float)y - CY) + CY;
    } else {
        int xo = p.flip ? (WW - 1 - x) : x;            // flip applied to warped result
        xs = (float)xo - p.dx;
        ys = (float)y - p.dy;
    }

    const float x0f = floorf(xs);
    const float y0f = floorf(ys);
    const float fx = xs - x0f;
    const float fy = ys - y0f;
    const int x0 = (int)x0f;
    const int y0 = (int)y0f;

    const int x0r = reflect_idx(x0,     WW);
    const int x1r = reflect_idx(x0 + 1, WW);
    const int y0r = reflect_idx(y0,     HH);
    const int y1r = reflect_idx(y0 + 1, HH);

    const float* img = src + (size_t)b * IMG_ELEMS;
    const float* Ia = img + (y0r * WW + x0r) * CC;
    const float* Ib = img + (y0r * WW + x1r) * CC;
    const float* Ic = img + (y1r * WW + x0r) * CC;
    const float* Id = img + (y1r * WW + x1r) * CC;

    float* o = dst + (size_t)b * IMG_ELEMS + (size_t)pix * CC;

    const float omfx = 1.0f - fx;
    const float omfy = 1.0f - fy;
    const float scale = (MODE == 0) ? SCALE_K : 1.0f;

#pragma unroll
    for (int ch = 0; ch < CC; ++ch) {
        float top = Ia[ch] * omfx + Ib[ch] * fx;
        float bot = Ic[ch] * omfx + Id[ch] * fx;
        o[ch] = (top * omfy + bot * fy) * scale;
    }
}

extern "C" void kernel_launch(void* const* d_in, const int* in_sizes, int n_in,
                              void* d_out, int out_size, void* d_ws, size_t ws_size,
                              hipStream_t stream) {
    const float* image   = (const float*)d_in[0];
    const float* angle_u = (const float*)d_in[1];
    const float* zoom_u  = (const float*)d_in[2];
    const float* shift_u = (const float*)d_in[3];
    const float* flip_u  = (const float*)d_in[4];
    float* out = (float*)d_out;

    float* tmp = (float*)d_ws;                          // B*H*W*C fp32 intermediate
    BatchParams* P = (BatchParams*)((char*)d_ws + (size_t)BB * IMG_ELEMS * sizeof(float));

    params_kernel<<<1, 64, 0, stream>>>(angle_u, zoom_u, shift_u, flip_u, P);

    dim3 grid(PIX / 256, BB);   // 196 x 64 blocks, 256 threads
    // pass 1: rescale + rotate   image -> d_out (used as tmp1)
    warp_kernel<0><<<grid, 256, 0, stream>>>(image, out, P);
    // pass 2: zoom               d_out -> d_ws
    warp_kernel<1><<<grid, 256, 0, stream>>>(out, tmp, P);
    // pass 3: translate + flip   d_ws -> d_out
    warp_kernel<2><<<grid, 256, 0, stream>>>(tmp, out, P);
}

// Round 2
// 51.459 us; speedup vs baseline: 1.5503x; 1.5503x over previous
//
#include <hip/hip_runtime.h>
#include <math.h>

// Problem constants (match reference)
#define BB 64
#define HH 224
#define WW 224
#define CC 3

constexpr float FACTOR  = 0.2f;
constexpr float SCALE_K = 1.0f / 255.0f;
constexpr float TWO_PI_F = 6.283185307179586f;
constexpr float CX = (WW - 1) * 0.5f;            // 111.5
constexpr float CY = (HH - 1) * 0.5f;            // 111.5
constexpr int PIX = HH * WW;                     // 50176
constexpr int IMG_ELEMS = PIX * CC;              // 150528

constexpr int TILES_X = WW / 16;                 // 14
constexpr int TILES_Y = HH / 16;                 // 14
constexpr int TILES_PER_IMG = TILES_X * TILES_Y; // 196
constexpr int NXCD = 8;
constexpr int BATCH_PER_XCD = BB / NXCD;         // 8
constexpr int NBLOCKS = BB * TILES_PER_IMG;      // 12544

struct BatchParams { float c, s, zh, zw, dx, dy; int flip, pad; };

__global__ void params_kernel(const float* __restrict__ angle_u,
                              const float* __restrict__ zoom_u,
                              const float* __restrict__ shift_u,
                              const float* __restrict__ flip_u,
                              BatchParams* __restrict__ P) {
    int b = threadIdx.x;
    if (b >= BB) return;
    BatchParams p;
    float t = (2.0f * angle_u[b] - 1.0f) * FACTOR;
    float theta = t * TWO_PI_F;
    p.c = cosf(theta);
    p.s = sinf(theta);
    p.zh = 1.0f + (2.0f * zoom_u[2 * b + 0] - 1.0f) * FACTOR;
    p.zw = 1.0f + (2.0f * zoom_u[2 * b + 1] - 1.0f) * FACTOR;
    p.dy = ((2.0f * shift_u[2 * b + 0] - 1.0f) * FACTOR) * (float)HH;
    p.dx = ((2.0f * shift_u[2 * b + 1] - 1.0f) * FACTOR) * (float)WW;
    p.flip = (flip_u[b] > 0.5f) ? 1 : 0;
    p.pad = 0;
    P[b] = p;
}

__device__ __forceinline__ int reflect_idx(int i, int n) {
    int m = i % (2 * n);
    if (m < 0) m += 2 * n;
    return (m >= n) ? (2 * n - 1 - m) : m;
}

// MODE 0: rotate (+rescale), MODE 1: zoom, MODE 2: translate (+flip)
// 1D grid of NBLOCKS; block i -> XCD i%8 (HW round-robin heuristic); batch b
// is assigned entirely to XCD b%8, identically in all three passes, so
// inter-pass reads hit the same L2 that the prior pass wrote.
template <int MODE>
__global__ __launch_bounds__(256)
void warp_kernel(const float* __restrict__ src, float* __restrict__ dst,
                 const BatchParams* __restrict__ P) {
    const int bid  = blockIdx.x;
    const int xcd  = bid & (NXCD - 1);
    const int slot = bid >> 3;                        // 0..1567
    const int bi   = slot / TILES_PER_IMG;            // batch index within XCD
    const int t    = slot - bi * TILES_PER_IMG;       // tile index 0..195
    const int b    = xcd + bi * NXCD;                 // batch
    const int ty   = t / TILES_X;
    const int tx   = t - ty * TILES_X;
    const int x    = tx * 16 + (threadIdx.x & 15);
    const int y    = ty * 16 + (threadIdx.x >> 4);

    const BatchParams p = P[b];

    float xs, ys;
    if (MODE == 0) {
        float rx = (float)x - CX;
        float ry = (float)y - CY;
        xs = p.c * rx - p.s * ry + CX;
        ys = p.s * rx + p.c * ry + CY;
    } else if (MODE == 1) {
        xs = p.zw * ((float)x - CX) + CX;
        ys = p.zh * ((float)y - CY) + CY;
    } else {
        int xo = p.flip ? (WW - 1 - x) : x;           // flip applied to warped result
        xs = (float)xo - p.dx;
        ys = (float)y - p.dy;
    }

    const float x0f = floorf(xs);
    const float y0f = floorf(ys);
    const float fx = xs - x0f;
    const float fy = ys - y0f;
    const int x0 = (int)x0f;
    const int y0 = (int)y0f;

    const int x0r = reflect_idx(x0,     WW);
    const int x1r = reflect_idx(x0 + 1, WW);
    const int y0r = reflect_idx(y0,     HH);
    const int y1r = reflect_idx(y0 + 1, HH);

    const float* img = src + (size_t)b * IMG_ELEMS;
    const float* Ia = img + (y0r * WW + x0r) * CC;
    const float* Ib = img + (y0r * WW + x1r) * CC;
    const float* Ic = img + (y1r * WW + x0r) * CC;
    const float* Id = img + (y1r * WW + x1r) * CC;

    float* o = dst + (size_t)b * IMG_ELEMS + ((size_t)y * WW + x) * CC;

    const float omfx = 1.0f - fx;
    const float omfy = 1.0f - fy;
    const float scale = (MODE == 0) ? SCALE_K : 1.0f;

#pragma unroll
    for (int ch = 0; ch < CC; ++ch) {
        float top = Ia[ch] * omfx + Ib[ch] * fx;
        float bot = Ic[ch] * omfx + Id[ch] * fx;
        o[ch] = (top * omfy + bot * fy) * scale;
    }
}

extern "C" void kernel_launch(void* const* d_in, const int* in_sizes, int n_in,
                              void* d_out, int out_size, void* d_ws, size_t ws_size,
                              hipStream_t stream) {
    const float* image   = (const float*)d_in[0];
    const float* angle_u = (const float*)d_in[1];
    const float* zoom_u  = (const float*)d_in[2];
    const float* shift_u = (const float*)d_in[3];
    const float* flip_u  = (const float*)d_in[4];
    float* out = (float*)d_out;

    float* tmp = (float*)d_ws;                          // B*H*W*C fp32 intermediate
    BatchParams* P = (BatchParams*)((char*)d_ws + (size_t)BB * IMG_ELEMS * sizeof(float));

    params_kernel<<<1, 64, 0, stream>>>(angle_u, zoom_u, shift_u, flip_u, P);

    // pass 1: rescale + rotate   image -> d_out (used as tmp1)
    warp_kernel<0><<<NBLOCKS, 256, 0, stream>>>(image, out, P);
    // pass 2: zoom               d_out -> d_ws
    warp_kernel<1><<<NBLOCKS, 256, 0, stream>>>(out, tmp, P);
    // pass 3: translate + flip   d_ws -> d_out
    warp_kernel<2><<<NBLOCKS, 256, 0, stream>>>(tmp, out, P);
}